// Round 1
// baseline (2586.214 us; speedup 1.0000x reference)
//
#include <hip/hip_runtime.h>

#define DEV __device__ __forceinline__

// ---------------- helpers ----------------

DEV float wsum(float v){
  #pragma unroll
  for (int o = 32; o > 0; o >>= 1) v += __shfl_xor(v, o, 64);
  return v;
}

DEV float gelu_f(float x){
  // tanh-approx gelu (JAX default approximate=True), NaN-safe for large |u|
  float u = 0.7978845608028654f * (x + 0.044715f * x * x * x);
  float e = __expf(2.f * u);
  float th = 1.f - 2.f / (e + 1.f);
  return 0.5f * x * (1.f + th);
}

// ---------------- LN over rows of 128 (wave per row) ----------------
// out1 may be null. in may alias out0 (in-place).
__global__ __launch_bounds__(256) void ln_kernel(const float* in,
    float* out0, float* out1,
    const float* __restrict__ g, const float* __restrict__ bb, int nrows)
{
  int w = threadIdx.x >> 6, l = threadIdx.x & 63;
  int row = blockIdx.x * 4 + w;
  if (row >= nrows) return;
  const float* rp = in + (size_t)row * 128;
  float v0 = rp[l], v1 = rp[l + 64];
  float m = wsum(v0 + v1) * 0.0078125f;
  float d0 = v0 - m, d1 = v1 - m;
  float var = wsum(d0 * d0 + d1 * d1) * 0.0078125f;
  float rs = rsqrtf(var + 1e-5f);
  float o0 = d0 * rs * g[l] + bb[l];
  float o1 = d1 * rs * g[l + 64] + bb[l + 64];
  size_t base = (size_t)row * 128;
  out0[base + l] = o0; out0[base + l + 64] = o1;
  if (out1){ out1[base + l] = o0; out1[base + l + 64] = o1; }
}

// ---------------- xmap = relu(X @ W + b), 25 rows/block ----------------
__global__ __launch_bounds__(256) void xmap_mm(const float* __restrict__ X,
    const float* __restrict__ W, const float* __restrict__ bias,
    float* __restrict__ out)
{
  __shared__ float xt[25 * 768];          // 76.8 KB
  const int t = threadIdx.x;
  const size_t rowbase = (size_t)blockIdx.x * 25;
  {
    const float4* Xg = (const float4*)(X + rowbase * 768);
    float4* xd = (float4*)xt;
    for (int i = t; i < 25 * 192; i += 256) xd[i] = Xg[i];
  }
  __syncthreads();
  const int c = t & 127, rh = t >> 7;
  const int r0 = rh ? 13 : 0, nr = rh ? 12 : 13;
  float acc[13];
  #pragma unroll
  for (int i = 0; i < 13; i++) acc[i] = 0.f;
  for (int k = 0; k < 768; k += 4){
    float w0 = W[(k+0)*128 + c], w1 = W[(k+1)*128 + c];
    float w2 = W[(k+2)*128 + c], w3 = W[(k+3)*128 + c];
    #pragma unroll
    for (int i = 0; i < 13; i++){
      if (i < nr){
        float4 xv = *(const float4*)&xt[(r0 + i) * 768 + k];
        acc[i] += xv.x*w0 + xv.y*w1 + xv.z*w2 + xv.w*w3;
      }
    }
  }
  float bc = bias[c];
  #pragma unroll
  for (int i = 0; i < 13; i++)
    if (i < nr) out[(rowbase + r0 + i) * 128 + c] = fmaxf(acc[i] + bc, 0.f);
}

// ---------------- LN rows of h in LDS (wave per row) ----------------
DEV void ln_rows_lds(float* hb, const float* g, const float* b, int w, int l){
  for (int r = w; r < 50; r += 4){
    float v0 = hb[r*128 + l], v1 = hb[r*128 + l + 64];
    float m = wsum(v0 + v1) * 0.0078125f;
    float d0 = v0 - m, d1 = v1 - m;
    float var = wsum(d0*d0 + d1*d1) * 0.0078125f;
    float rs = rsqrtf(var + 1e-5f);
    hb[r*128 + l]      = d0 * rs * g[l] + b[l];
    hb[r*128 + l + 64] = d1 * rs * g[l + 64] + b[l + 64];
  }
}

// ---------------- full encoder, one block per sequence ----------------
__global__ __launch_bounds__(256) void encoder_kernel(
    const float* __restrict__ emb, const int* __restrict__ itemid,
    const float* __restrict__ mask, const float* __restrict__ pos,
    const float* __restrict__ ln0g, const float* __restrict__ ln0b,
    const float* __restrict__ Wqkv_, const float* __restrict__ bqkv_,
    const float* __restrict__ Wo_, const float* __restrict__ bo_,
    const float* __restrict__ ln1g_, const float* __restrict__ ln1b_,
    const float* __restrict__ W1_, const float* __restrict__ b1_,
    const float* __restrict__ W2_, const float* __restrict__ b2_,
    const float* __restrict__ ln2g_, const float* __restrict__ ln2b_,
    float* __restrict__ outT)     // [128][256] transposed last-token emb
{
  __shared__ float h[50 * 128];     // 25.6 KB
  __shared__ float scr[50 * 512];   // 102.4 KB: qkvT[384][50] + S[2][50][50]; reused as O and f1
  const int t = threadIdx.x, b = blockIdx.x;
  const int w = t >> 6, l = t & 63;

  // gather + pos + LN0 (wave per row; each wave owns its rows -> no sync needed inside)
  for (int r = w; r < 50; r += 4){
    int it = itemid[b*50 + r];
    const float* er = emb + (size_t)it * 128;
    float v0 = er[l]      + pos[r*128 + l];
    float v1 = er[l + 64] + pos[r*128 + l + 64];
    float m = wsum(v0 + v1) * 0.0078125f;
    float d0 = v0 - m, d1 = v1 - m;
    float var = wsum(d0*d0 + d1*d1) * 0.0078125f;
    float rs = rsqrtf(var + 1e-5f);
    h[r*128 + l]      = d0 * rs * ln0g[l] + ln0b[l];
    h[r*128 + l + 64] = d1 * rs * ln0g[l + 64] + ln0b[l + 64];
  }
  __syncthreads();

  for (int lay = 0; lay < 2; ++lay){
    const float* Wq  = Wqkv_ + lay * 128 * 384;
    const float* bq  = bqkv_ + lay * 384;
    const float* Wo  = Wo_   + lay * 128 * 128;
    const float* bo  = bo_   + lay * 128;
    const float* g1  = ln1g_ + lay * 128;
    const float* b1n = ln1b_ + lay * 128;
    const float* W1  = W1_   + lay * 128 * 512;
    const float* b1f = b1_   + lay * 512;
    const float* W2  = W2_   + lay * 512 * 128;
    const float* b2f = b2_   + lay * 128;
    const float* g2  = ln2g_ + lay * 128;
    const float* b2n = ln2b_ + lay * 128;

    // ---- QKV (transposed out): scr[c*50 + r] = sum_k h[r][k]*Wq[k][c] + bq[c]
    for (int p = 0; p < 3; p++){
      int slot = p * 256 + t;            // 0..767 = 384 cols x 2 row-halves
      int rh = slot >= 384 ? 1 : 0;
      int c  = slot - 384 * rh;
      int r0 = rh * 25;
      float acc[25];
      #pragma unroll
      for (int i = 0; i < 25; i++) acc[i] = 0.f;
      for (int k = 0; k < 128; k += 4){
        float w0 = Wq[(k+0)*384 + c], w1 = Wq[(k+1)*384 + c];
        float w2 = Wq[(k+2)*384 + c], w3 = Wq[(k+3)*384 + c];
        #pragma unroll
        for (int i = 0; i < 25; i++){
          float4 hv = *(const float4*)&h[(r0 + i)*128 + k];   // wave-uniform broadcast
          acc[i] += hv.x*w0 + hv.y*w1 + hv.z*w2 + hv.w*w3;
        }
      }
      float bc = bq[c];
      #pragma unroll
      for (int i = 0; i < 25; i++) scr[c*50 + r0 + i] = acc[i] + bc;
    }
    __syncthreads();

    // ---- S = tril/mask softmax input; S at scr+19200, [2][50][50]
    float* S = scr + 19200;
    for (int e = t; e < 5000; e += 256){
      int hd = e / 2500; int rem = e - hd * 2500;
      int qi = rem / 50; int ki = rem - qi * 50;
      float s = -1e9f;
      if (ki <= qi && mask[b*50 + ki] != 0.f){
        float d = 0.f;
        #pragma unroll
        for (int j = 0; j < 64; j++)
          d += scr[(hd*64 + j)*50 + qi] * scr[(128 + hd*64 + j)*50 + ki];
        s = d * 0.125f;   // 1/sqrt(64)
      }
      S[e] = s;
    }
    __syncthreads();

    // ---- softmax over each of the 100 rows
    if (t < 100){
      int hd = t / 50, qi = t - hd * 50;
      float* sp = S + hd * 2500 + qi * 50;
      float mx = -1e30f;
      for (int i = 0; i < 50; i++) mx = fmaxf(mx, sp[i]);
      float sum = 0.f;
      for (int i = 0; i < 50; i++){ float pv = __expf(sp[i] - mx); sp[i] = pv; sum += pv; }
      float inv = 1.f / sum;
      for (int i = 0; i < 50; i++) sp[i] *= inv;
    }
    __syncthreads();

    // ---- O[qi*128 + cd] into scr[0..6400) (qT region is dead now)
    for (int e = t; e < 6400; e += 256){
      int qi = e >> 7, cd = e & 127;
      const float* vp = scr + (256 + cd) * 50;
      const float* pp = S + (cd >> 6) * 2500 + qi * 50;
      float o = 0.f;
      for (int ki = 0; ki <= qi; ++ki) o += pp[ki] * vp[ki];
      scr[qi*128 + cd] = o;
    }
    __syncthreads();

    // ---- h += O @ Wo + bo
    {
      int c = t & 127, rh = t >> 7, r0 = rh * 25;
      float acc[25];
      #pragma unroll
      for (int i = 0; i < 25; i++) acc[i] = 0.f;
      for (int k = 0; k < 128; k += 4){
        float w0 = Wo[(k+0)*128 + c], w1 = Wo[(k+1)*128 + c];
        float w2 = Wo[(k+2)*128 + c], w3 = Wo[(k+3)*128 + c];
        #pragma unroll
        for (int i = 0; i < 25; i++){
          float4 ov = *(const float4*)&scr[(r0 + i)*128 + k];
          acc[i] += ov.x*w0 + ov.y*w1 + ov.z*w2 + ov.w*w3;
        }
      }
      float bc = bo[c];
      #pragma unroll
      for (int i = 0; i < 25; i++) h[(r0 + i)*128 + c] += acc[i] + bc;
    }
    __syncthreads();
    ln_rows_lds(h, g1, b1n, w, l);
    __syncthreads();

    // ---- f1 = gelu(h @ W1 + b1) -> scr[50][512]
    for (int p = 0; p < 4; p++){
      int slot = p * 256 + t;           // 0..1023 = 512 cols x 2 row-halves
      int c = slot & 511, rh = slot >> 9, r0 = rh * 25;
      float acc[25];
      #pragma unroll
      for (int i = 0; i < 25; i++) acc[i] = 0.f;
      for (int k = 0; k < 128; k += 4){
        float w0 = W1[(k+0)*512 + c], w1 = W1[(k+1)*512 + c];
        float w2 = W1[(k+2)*512 + c], w3 = W1[(k+3)*512 + c];
        #pragma unroll
        for (int i = 0; i < 25; i++){
          float4 hv = *(const float4*)&h[(r0 + i)*128 + k];
          acc[i] += hv.x*w0 + hv.y*w1 + hv.z*w2 + hv.w*w3;
        }
      }
      float bc = b1f[c];
      #pragma unroll
      for (int i = 0; i < 25; i++) scr[(r0 + i)*512 + c] = gelu_f(acc[i] + bc);
    }
    __syncthreads();

    // ---- h += f1 @ W2 + b2
    {
      int c = t & 127, rh = t >> 7, r0 = rh * 25;
      float acc[25];
      #pragma unroll
      for (int i = 0; i < 25; i++) acc[i] = 0.f;
      for (int k = 0; k < 512; k += 4){
        float w0 = W2[(k+0)*128 + c], w1 = W2[(k+1)*128 + c];
        float w2 = W2[(k+2)*128 + c], w3 = W2[(k+3)*128 + c];
        #pragma unroll
        for (int i = 0; i < 25; i++){
          float4 fv = *(const float4*)&scr[(r0 + i)*512 + k];
          acc[i] += fv.x*w0 + fv.y*w1 + fv.z*w2 + fv.w*w3;
        }
      }
      float bc = b2f[c];
      #pragma unroll
      for (int i = 0; i < 25; i++) h[(r0 + i)*128 + c] += acc[i] + bc;
    }
    __syncthreads();
    ln_rows_lds(h, g2, b2n, w, l);
    __syncthreads();
  }

  // ---- extract last valid token, store transposed [feature][session]
  if (t < 128){
    float sm = 0.f;
    for (int i = 0; i < 50; i++) sm += mask[b*50 + i];
    int idx = (int)sm - 1;
    idx = max(0, min(49, idx));
    outT[t * 256 + b] = h[idx * 128 + t];
  }
}

// ---------------- scores: 16 items x 256 sessions per block ----------------
__global__ __launch_bounds__(256) void scores_kernel(
    const float* __restrict__ seT, const float* __restrict__ sfT,  // [128][256]
    const float* __restrict__ ie,  const float* __restrict__ xm,   // [50000][128]
    float* __restrict__ sc, float* __restrict__ s1, float* __restrict__ s2)
{
  __shared__ float iet[16 * 128];
  __shared__ float xmt[16 * 128];
  const int t = threadIdx.x;
  const size_t j0 = (size_t)blockIdx.x * 16;
  {
    const float4* ig = (const float4*)(ie + j0 * 128);
    const float4* xg = (const float4*)(xm + j0 * 128);
    float4* a = (float4*)iet; float4* c4 = (float4*)xmt;
    for (int i = t; i < 512; i += 256){ a[i] = ig[i]; c4[i] = xg[i]; }
  }
  __syncthreads();
  float a1[16], a2[16];
  #pragma unroll
  for (int j = 0; j < 16; j++){ a1[j] = 0.f; a2[j] = 0.f; }
  for (int k = 0; k < 128; k += 4){
    float se0 = seT[(k+0)*256 + t], se1 = seT[(k+1)*256 + t];
    float se2 = seT[(k+2)*256 + t], se3 = seT[(k+3)*256 + t];
    float sf0 = sfT[(k+0)*256 + t], sf1 = sfT[(k+1)*256 + t];
    float sf2 = sfT[(k+2)*256 + t], sf3 = sfT[(k+3)*256 + t];
    #pragma unroll
    for (int j = 0; j < 16; j++){
      float4 iv = *(const float4*)&iet[j*128 + k];   // wave-uniform broadcast
      float4 xv = *(const float4*)&xmt[j*128 + k];
      a1[j] += iv.x*se0 + iv.y*se1 + iv.z*se2 + iv.w*se3;
      a2[j] += xv.x*sf0 + xv.y*sf1 + xv.z*sf2 + xv.w*sf3;
    }
  }
  size_t rb = (size_t)t * 50000 + j0;
  #pragma unroll
  for (int j = 0; j < 16; j += 4){
    float4 v1 = make_float4(a1[j], a1[j+1], a1[j+2], a1[j+3]);
    float4 v2 = make_float4(a2[j]*10.f, a2[j+1]*10.f, a2[j+2]*10.f, a2[j+3]*10.f);
    float4 vs = make_float4(0.5f*(v1.x+v2.x), 0.5f*(v1.y+v2.y),
                            0.5f*(v1.z+v2.z), 0.5f*(v1.w+v2.w));
    *(float4*)&s1[rb + j] = v1;
    *(float4*)&s2[rb + j] = v2;
    *(float4*)&sc[rb + j] = vs;
  }
}

// ---------------- launcher ----------------
extern "C" void kernel_launch(void* const* d_in, const int* in_sizes, int n_in,
                              void* d_out, int out_size, void* d_ws, size_t ws_size,
                              hipStream_t stream)
{
  const float* x       = (const float*)d_in[0];
  const int*   itemid  = (const int*)d_in[4];
  const float* mask    = (const float*)d_in[5];
  const float* id_emb  = (const float*)d_in[6];
  const float* id_g    = (const float*)d_in[7];
  const float* id_b    = (const float*)d_in[8];
  const float* text_W  = (const float*)d_in[9];
  const float* text_b  = (const float*)d_in[10];
  const float* text_g  = (const float*)d_in[11];
  const float* text_bb = (const float*)d_in[12];

  float* out = (float*)d_out;
  float* o_scores = out;                      // [256][50000]
  float* o_s1     = out + 12800000;
  float* o_s2     = out + 25600000;
  float* o_item   = out + 38400000;           // [50000][128]
  float* o_gnn    = out + 44800000;
  float* o_xmap   = out + 51200000;

  float* seT = (float*)d_ws;                  // [128][256]
  float* sfT = seT + 128 * 256;

  ln_kernel<<<12500, 256, 0, stream>>>(id_emb, o_item, o_gnn, id_g, id_b, 50000);
  xmap_mm<<<2000, 256, 0, stream>>>(x, text_W, text_b, o_xmap);
  ln_kernel<<<12500, 256, 0, stream>>>(o_xmap, o_xmap, nullptr, text_g, text_bb, 50000);

  encoder_kernel<<<256, 256, 0, stream>>>(o_item, itemid, mask,
      (const float*)d_in[13], (const float*)d_in[14], (const float*)d_in[15],
      (const float*)d_in[16], (const float*)d_in[17], (const float*)d_in[18],
      (const float*)d_in[19], (const float*)d_in[20], (const float*)d_in[21],
      (const float*)d_in[22], (const float*)d_in[23], (const float*)d_in[24],
      (const float*)d_in[25], (const float*)d_in[26], (const float*)d_in[27],
      seT);
  encoder_kernel<<<256, 256, 0, stream>>>(o_xmap, itemid, mask,
      (const float*)d_in[28], (const float*)d_in[29], (const float*)d_in[30],
      (const float*)d_in[31], (const float*)d_in[32], (const float*)d_in[33],
      (const float*)d_in[34], (const float*)d_in[35], (const float*)d_in[36],
      (const float*)d_in[37], (const float*)d_in[38], (const float*)d_in[39],
      (const float*)d_in[40], (const float*)d_in[41], (const float*)d_in[42],
      sfT);

  scores_kernel<<<3125, 256, 0, stream>>>(seT, sfT, o_item, o_xmap,
                                          o_scores, o_s1, o_s2);
}

// Round 2
// 1074.551 us; speedup vs baseline: 2.4068x; 2.4068x over previous
//
#include <hip/hip_runtime.h>

#define DEV __device__ __forceinline__

typedef float f32x4 __attribute__((ext_vector_type(4)));
typedef __bf16 bf16x8 __attribute__((ext_vector_type(8)));
#define MFMA16(a,b,c) __builtin_amdgcn_mfma_f32_16x16x32_bf16(a,b,c,0,0,0)

#define LSTRIDE 132   // hf fp32 row stride (132 mod 32 = 4 -> conflict-light)
#define ASTRIDE 136   // bf16 A-buffer stride (272 B, 16B-aligned, 2-way max)
#define QSTRIDE 72    // bf16 qkv/p stride (144 B, 16B-aligned)

DEV float wsum(float v){
  #pragma unroll
  for (int o = 32; o > 0; o >>= 1) v += __shfl_xor(v, o, 64);
  return v;
}

DEV float gelu_f(float x){
  float u = 0.7978845608028654f * (x + 0.044715f * x * x * x);
  float e = __expf(2.f * u);
  float th = 1.f - 2.f / (e + 1.f);
  return 0.5f * x * (1.f + th);
}

// ---------------- LN over rows of 128 (wave per row) ----------------
__global__ __launch_bounds__(256) void ln_kernel(const float* in,
    float* out0, float* out1,
    const float* __restrict__ g, const float* __restrict__ bb, int nrows)
{
  int w = threadIdx.x >> 6, l = threadIdx.x & 63;
  int row = blockIdx.x * 4 + w;
  if (row >= nrows) return;
  const float* rp = in + (size_t)row * 128;
  float v0 = rp[l], v1 = rp[l + 64];
  float m = wsum(v0 + v1) * 0.0078125f;
  float d0 = v0 - m, d1 = v1 - m;
  float var = wsum(d0 * d0 + d1 * d1) * 0.0078125f;
  float rs = rsqrtf(var + 1e-5f);
  float o0 = d0 * rs * g[l] + bb[l];
  float o1 = d1 * rs * g[l + 64] + bb[l + 64];
  size_t base = (size_t)row * 128;
  out0[base + l] = o0; out0[base + l + 64] = o1;
  if (out1){ out1[base + l] = o0; out1[base + l + 64] = o1; }
}

// ---------------- weight prep: fp32 [K][N] -> bf16 fragment-major ----------
// dst[((mat*tpm + nt*(K/32)+kt)*64 + lane)*8 + j] = W[kt*32+(lane>>4)*8+j][nt*16+(lane&15)]
__global__ __launch_bounds__(256) void prep_w(
    const float* __restrict__ Wa, const float* __restrict__ Wb,
    __bf16* __restrict__ dst, int K, int N, int nmat)
{
  int tid = blockIdx.x * 256 + threadIdx.x;
  int tpm = (N >> 4) * (K >> 5);
  if (tid >= nmat * tpm * 64) return;
  int lane = tid & 63;
  int tile = (tid >> 6) % tpm;
  int mat  = tid / (tpm * 64);
  const float* W;
  if (nmat == 1) W = Wa;
  else W = ((mat >> 1) ? Wb : Wa) + (size_t)(mat & 1) * K * N;
  int kdiv = K >> 5;
  int nt = tile / kdiv, kt = tile - nt * kdiv;
  int col  = nt * 16 + (lane & 15);
  int krow = kt * 32 + (lane >> 4) * 8;
  __bf16 v[8];
  #pragma unroll
  for (int j = 0; j < 8; j++) v[j] = (__bf16)W[(size_t)(krow + j) * N + col];
  *(bf16x8*)(dst + (size_t)tid * 8) = *(bf16x8*)v;
}

// ---------------- xmap = relu(X @ textW + b) via MFMA ----------------
__global__ __launch_bounds__(256) void xmap_mfma(
    const float* __restrict__ X, const __bf16* __restrict__ wt,
    const float* __restrict__ bias, float* __restrict__ out)
{
  __shared__ __bf16 xb[64 * ASTRIDE];
  const int t = threadIdx.x, w = t >> 6, l = t & 63, lm = l & 15, quad = l >> 4;
  const int r0 = blockIdx.x * 64;
  f32x4 acc[8];
  #pragma unroll
  for (int nt = 0; nt < 8; nt++) acc[nt] = (f32x4){0.f,0.f,0.f,0.f};
  for (int kc = 0; kc < 6; kc++){
    for (int i = t; i < 64 * 32; i += 256){
      int r = i >> 5, c4 = (i & 31) * 4;
      float4 v = make_float4(0.f,0.f,0.f,0.f);
      if (r0 + r < 50000) v = *(const float4*)&X[(size_t)(r0 + r) * 768 + kc * 128 + c4];
      xb[r*ASTRIDE + c4 + 0] = (__bf16)v.x;
      xb[r*ASTRIDE + c4 + 1] = (__bf16)v.y;
      xb[r*ASTRIDE + c4 + 2] = (__bf16)v.z;
      xb[r*ASTRIDE + c4 + 3] = (__bf16)v.w;
    }
    __syncthreads();
    bf16x8 af[4];
    #pragma unroll
    for (int kt = 0; kt < 4; kt++)
      af[kt] = *(const bf16x8*)&xb[(w*16 + lm)*ASTRIDE + kt*32 + quad*8];
    #pragma unroll
    for (int nt = 0; nt < 8; nt++)
      #pragma unroll
      for (int kt = 0; kt < 4; kt++)
        acc[nt] = MFMA16(af[kt], *(const bf16x8*)(wt + ((size_t)(nt*24 + kc*4 + kt)*64 + l)*8), acc[nt]);
    __syncthreads();
  }
  #pragma unroll
  for (int nt = 0; nt < 8; nt++){
    int n = nt*16 + lm;
    float bs = bias[n];
    #pragma unroll
    for (int r = 0; r < 4; r++){
      int row = r0 + w*16 + quad*4 + r;
      if (row < 50000) out[(size_t)row*128 + n] = fmaxf(acc[nt][r] + bs, 0.f);
    }
  }
}

// ---------------- encoder params ----------------
struct EncP {
  const float *pos, *ln0g, *ln0b, *bqkv, *bo, *ln1g, *ln1b, *b1, *b2, *ln2g, *ln2b;
  const __bf16 *wq, *wo, *w1, *w2;  // fragment-major bases (layer strides: 49152/16384/65536/65536)
  const float* emb;
  float* outT;
};

DEV void ln_rows(float* hb, const float* g, const float* bb, int w, int l){
  for (int r = w; r < 50; r += 4){
    float v0 = hb[r*LSTRIDE + l], v1 = hb[r*LSTRIDE + l + 64];
    float m = wsum(v0 + v1) * 0.0078125f;
    float d0 = v0 - m, d1 = v1 - m;
    float var = wsum(d0*d0 + d1*d1) * 0.0078125f;
    float rs = rsqrtf(var + 1e-5f);
    hb[r*LSTRIDE + l]      = d0 * rs * g[l] + bb[l];
    hb[r*LSTRIDE + l + 64] = d1 * rs * g[l + 64] + bb[l + 64];
  }
}

// ---------------- full encoder (MFMA), one block per sequence ----------------
__global__ __launch_bounds__(256) void encoder_mfma(
    EncP P0, EncP P1, const int* __restrict__ itemid, const float* __restrict__ mask)
{
  EncP P = (blockIdx.x < 256) ? P0 : P1;
  const int b = blockIdx.x & 255;
  const int t = threadIdx.x, w = t >> 6, l = t & 63;
  const int lm = l & 15, quad = l >> 4;
  const int mb = w * 16;        // this wave's M band
  const int am = mb + lm;       // A-fragment row for this lane

  __shared__ float  hf[50 * LSTRIDE];        // fp32 residual stream
  __shared__ __bf16 ab[64 * ASTRIDE];        // bf16 A staging (h / O)
  __shared__ __bf16 qrm[2 * 64 * QSTRIDE];   // Q row-major [hd][q][d]; reused as f1 chunk buf
  __shared__ __bf16 krm[2 * 64 * QSTRIDE];   // K row-major [hd][ki][d]
  __shared__ __bf16 vtm[2 * 64 * QSTRIDE];   // V transposed [hd][d][ki]
  __shared__ __bf16 prm[2 * 64 * QSTRIDE];   // P row-major [hd][q][ki]
  __shared__ float  maskv[64];

  if (t < 64) maskv[t] = (t < 50) ? mask[b*50 + t] : 0.f;

  // gather + pos + LN0 (wave-per-row)
  for (int r = w; r < 50; r += 4){
    int it = itemid[b*50 + r];
    const float* er = P.emb + (size_t)it * 128;
    float v0 = er[l]      + P.pos[r*128 + l];
    float v1 = er[l + 64] + P.pos[r*128 + l + 64];
    float m = wsum(v0 + v1) * 0.0078125f;
    float d0 = v0 - m, d1 = v1 - m;
    float var = wsum(d0*d0 + d1*d1) * 0.0078125f;
    float rs = rsqrtf(var + 1e-5f);
    hf[r*LSTRIDE + l]      = d0 * rs * P.ln0g[l] + P.ln0b[l];
    hf[r*LSTRIDE + l + 64] = d1 * rs * P.ln0g[l + 64] + P.ln0b[l + 64];
  }
  __syncthreads();

  for (int lay = 0; lay < 2; ++lay){
    const __bf16* wq = P.wq + lay * 49152;
    const __bf16* wo = P.wo + lay * 16384;
    const __bf16* w1 = P.w1 + lay * 65536;
    const __bf16* w2 = P.w2 + lay * 65536;
    const float* bq  = P.bqkv + lay * 384;
    const float* bo  = P.bo   + lay * 128;
    const float* g1  = P.ln1g + lay * 128;
    const float* b1n = P.ln1b + lay * 128;
    const float* b1f = P.b1   + lay * 512;
    const float* b2f = P.b2   + lay * 128;
    const float* g2  = P.ln2g + lay * 128;
    const float* b2n = P.ln2b + lay * 128;

    // convert hf -> ab (rows >= 50 zero)
    for (int i = t; i < 64 * 128; i += 256){
      int r = i >> 7, c = i & 127;
      ab[r*ASTRIDE + c] = (__bf16)((r < 50) ? hf[r*LSTRIDE + c] : 0.f);
    }
    __syncthreads();

    // ---- QKV GEMM: [64x128] @ [128x384] ----
    {
      bf16x8 af[4];
      #pragma unroll
      for (int kt = 0; kt < 4; kt++)
        af[kt] = *(const bf16x8*)&ab[am*ASTRIDE + kt*32 + quad*8];
      for (int nt = 0; nt < 24; nt++){
        f32x4 acc = (f32x4){0.f,0.f,0.f,0.f};
        #pragma unroll
        for (int kt = 0; kt < 4; kt++)
          acc = MFMA16(af[kt], *(const bf16x8*)(wq + ((size_t)(nt*4 + kt)*64 + l)*8), acc);
        int n = nt*16 + lm;
        float bias = bq[n];
        int part = n >> 7, hd = (n >> 6) & 1, d = n & 63;
        __bf16* dq = &qrm[hd*64*QSTRIDE];
        __bf16* dk = &krm[hd*64*QSTRIDE];
        __bf16* dv = &vtm[hd*64*QSTRIDE];
        #pragma unroll
        for (int r = 0; r < 4; r++){
          int m = mb + quad*4 + r;
          float v = acc[r] + bias;
          if (part == 0)      dq[m*QSTRIDE + d] = (__bf16)v;
          else if (part == 1) dk[m*QSTRIDE + d] = (__bf16)v;
          else                dv[d*QSTRIDE + m] = (__bf16)v;   // V transposed
        }
      }
    }
    __syncthreads();

    // ---- attention: this wave handles q-rows [mb, mb+16), both heads ----
    for (int hd = 0; hd < 2; hd++){
      const __bf16* q_ = &qrm[hd*64*QSTRIDE];
      const __bf16* k_ = &krm[hd*64*QSTRIDE];
      const __bf16* v_ = &vtm[hd*64*QSTRIDE];
      __bf16* p_       = &prm[hd*64*QSTRIDE];
      bf16x8 aq0 = *(const bf16x8*)&q_[am*QSTRIDE + quad*8];
      bf16x8 aq1 = *(const bf16x8*)&q_[am*QSTRIDE + 32 + quad*8];
      f32x4 sf[4];
      #pragma unroll
      for (int nt = 0; nt < 4; nt++){
        f32x4 acc = (f32x4){0.f,0.f,0.f,0.f};
        acc = MFMA16(aq0, *(const bf16x8*)&k_[(nt*16 + lm)*QSTRIDE + quad*8], acc);
        acc = MFMA16(aq1, *(const bf16x8*)&k_[(nt*16 + lm)*QSTRIDE + 32 + quad*8], acc);
        sf[nt] = acc;
      }
      #pragma unroll
      for (int r = 0; r < 4; r++){
        int q = mb + quad*4 + r;
        float sv[4];
        float mx = -3e38f;
        #pragma unroll
        for (int nt = 0; nt < 4; nt++){
          int ki = nt*16 + lm;
          float s = sf[nt][r] * 0.125f;
          bool keep = (ki <= q) && (maskv[ki] != 0.f);
          s = keep ? s : -1e9f;
          sv[nt] = s; mx = fmaxf(mx, s);
        }
        #pragma unroll
        for (int o = 1; o < 16; o <<= 1) mx = fmaxf(mx, __shfl_xor(mx, o, 64));
        float sum = 0.f;
        #pragma unroll
        for (int nt = 0; nt < 4; nt++){ float p = __expf(sv[nt] - mx); sv[nt] = p; sum += p; }
        #pragma unroll
        for (int o = 1; o < 16; o <<= 1) sum += __shfl_xor(sum, o, 64);
        float inv = 1.f / sum;
        #pragma unroll
        for (int nt = 0; nt < 4; nt++)
          p_[q*QSTRIDE + nt*16 + lm] = (__bf16)(sv[nt] * inv);
      }
      // PV -> O into ab (own band only)
      bf16x8 ap0 = *(const bf16x8*)&p_[am*QSTRIDE + quad*8];
      bf16x8 ap1 = *(const bf16x8*)&p_[am*QSTRIDE + 32 + quad*8];
      #pragma unroll
      for (int nt = 0; nt < 4; nt++){
        f32x4 acc = (f32x4){0.f,0.f,0.f,0.f};
        acc = MFMA16(ap0, *(const bf16x8*)&v_[(nt*16 + lm)*QSTRIDE + quad*8], acc);
        acc = MFMA16(ap1, *(const bf16x8*)&v_[(nt*16 + lm)*QSTRIDE + 32 + quad*8], acc);
        int dcol = hd*64 + nt*16 + lm;
        #pragma unroll
        for (int r = 0; r < 4; r++)
          ab[(mb + quad*4 + r)*ASTRIDE + dcol] = (__bf16)acc[r];
      }
    }

    // ---- h += O @ Wo + bo ----
    {
      bf16x8 af[4];
      #pragma unroll
      for (int kt = 0; kt < 4; kt++)
        af[kt] = *(const bf16x8*)&ab[am*ASTRIDE + kt*32 + quad*8];
      #pragma unroll
      for (int nt = 0; nt < 8; nt++){
        f32x4 acc = (f32x4){0.f,0.f,0.f,0.f};
        #pragma unroll
        for (int kt = 0; kt < 4; kt++)
          acc = MFMA16(af[kt], *(const bf16x8*)(wo + ((size_t)(nt*4 + kt)*64 + l)*8), acc);
        int n = nt*16 + lm;
        float bias = bo[n];
        #pragma unroll
        for (int r = 0; r < 4; r++){
          int m = mb + quad*4 + r;
          if (m < 50) hf[m*LSTRIDE + n] += acc[r] + bias;
        }
      }
    }
    __syncthreads();
    ln_rows(hf, g1, b1n, w, l);
    __syncthreads();

    // convert hf -> ab (post-LN1 h)
    for (int i = t; i < 64 * 128; i += 256){
      int r = i >> 7, c = i & 127;
      ab[r*ASTRIDE + c] = (__bf16)((r < 50) ? hf[r*LSTRIDE + c] : 0.f);
    }
    __syncthreads();

    // ---- FFN fused over FF chunks of 128 ----
    {
      bf16x8 ah[4];
      #pragma unroll
      for (int kt = 0; kt < 4; kt++)
        ah[kt] = *(const bf16x8*)&ab[am*ASTRIDE + kt*32 + quad*8];
      f32x4 acc2[8];
      #pragma unroll
      for (int nt = 0; nt < 8; nt++) acc2[nt] = (f32x4){0.f,0.f,0.f,0.f};
      __bf16* ab2 = qrm;  // attention Q buffer is dead; 8704 <= 9216 shorts
      for (int ch = 0; ch < 4; ch++){
        #pragma unroll
        for (int nt = 0; nt < 8; nt++){
          f32x4 acc = (f32x4){0.f,0.f,0.f,0.f};
          #pragma unroll
          for (int kt = 0; kt < 4; kt++)
            acc = MFMA16(ah[kt], *(const bf16x8*)(w1 + ((size_t)((ch*8 + nt)*4 + kt)*64 + l)*8), acc);
          int n = ch*128 + nt*16 + lm;
          float bias = b1f[n];
          #pragma unroll
          for (int r = 0; r < 4; r++)
            ab2[(mb + quad*4 + r)*ASTRIDE + nt*16 + lm] = (__bf16)gelu_f(acc[r] + bias);
        }
        bf16x8 a2[4];
        #pragma unroll
        for (int kt = 0; kt < 4; kt++)
          a2[kt] = *(const bf16x8*)&ab2[am*ASTRIDE + kt*32 + quad*8];
        #pragma unroll
        for (int nt = 0; nt < 8; nt++)
          #pragma unroll
          for (int kt = 0; kt < 4; kt++)
            acc2[nt] = MFMA16(a2[kt], *(const bf16x8*)(w2 + ((size_t)(nt*16 + ch*4 + kt)*64 + l)*8), acc2[nt]);
      }
      #pragma unroll
      for (int nt = 0; nt < 8; nt++){
        int n = nt*16 + lm;
        float bias = b2f[n];
        #pragma unroll
        for (int r = 0; r < 4; r++){
          int m = mb + quad*4 + r;
          if (m < 50) hf[m*LSTRIDE + n] += acc2[nt][r] + bias;
        }
      }
    }
    __syncthreads();
    ln_rows(hf, g2, b2n, w, l);
    __syncthreads();
  }

  // last valid token -> transposed session emb [128][256]
  if (t < 128){
    float sm = 0.f;
    for (int i = 0; i < 50; i++) sm += maskv[i];
    int idx = min(49, max(0, (int)sm - 1));
    P.outT[t*256 + b] = hf[idx*LSTRIDE + t];
  }
}

// ---------------- scores: 16 items x 256 sessions per block ----------------
__global__ __launch_bounds__(256) void scores_kernel(
    const float* __restrict__ seT, const float* __restrict__ sfT,
    const float* __restrict__ ie,  const float* __restrict__ xm,
    float* __restrict__ sc, float* __restrict__ s1, float* __restrict__ s2)
{
  __shared__ float iet[16 * 128];
  __shared__ float xmt[16 * 128];
  const int t = threadIdx.x;
  const size_t j0 = (size_t)blockIdx.x * 16;
  {
    const float4* ig = (const float4*)(ie + j0 * 128);
    const float4* xg = (const float4*)(xm + j0 * 128);
    float4* a = (float4*)iet; float4* c4 = (float4*)xmt;
    for (int i = t; i < 512; i += 256){ a[i] = ig[i]; c4[i] = xg[i]; }
  }
  __syncthreads();
  float a1[16], a2[16];
  #pragma unroll
  for (int j = 0; j < 16; j++){ a1[j] = 0.f; a2[j] = 0.f; }
  for (int k = 0; k < 128; k += 4){
    float se0 = seT[(k+0)*256 + t], se1 = seT[(k+1)*256 + t];
    float se2 = seT[(k+2)*256 + t], se3 = seT[(k+3)*256 + t];
    float sf0 = sfT[(k+0)*256 + t], sf1 = sfT[(k+1)*256 + t];
    float sf2 = sfT[(k+2)*256 + t], sf3 = sfT[(k+3)*256 + t];
    #pragma unroll
    for (int j = 0; j < 16; j++){
      float4 iv = *(const float4*)&iet[j*128 + k];
      float4 xv = *(const float4*)&xmt[j*128 + k];
      a1[j] += iv.x*se0 + iv.y*se1 + iv.z*se2 + iv.w*se3;
      a2[j] += xv.x*sf0 + xv.y*sf1 + xv.z*sf2 + xv.w*sf3;
    }
  }
  size_t rb = (size_t)t * 50000 + j0;
  #pragma unroll
  for (int j = 0; j < 16; j += 4){
    float4 v1 = make_float4(a1[j], a1[j+1], a1[j+2], a1[j+3]);
    float4 v2 = make_float4(a2[j]*10.f, a2[j+1]*10.f, a2[j+2]*10.f, a2[j+3]*10.f);
    float4 vs = make_float4(0.5f*(v1.x+v2.x), 0.5f*(v1.y+v2.y),
                            0.5f*(v1.z+v2.z), 0.5f*(v1.w+v2.w));
    *(float4*)&s1[rb + j] = v1;
    *(float4*)&s2[rb + j] = v2;
    *(float4*)&sc[rb + j] = vs;
  }
}

// ---------------- launcher ----------------
extern "C" void kernel_launch(void* const* d_in, const int* in_sizes, int n_in,
                              void* d_out, int out_size, void* d_ws, size_t ws_size,
                              hipStream_t stream)
{
  const float* x       = (const float*)d_in[0];
  const int*   itemid  = (const int*)d_in[4];
  const float* mask    = (const float*)d_in[5];
  const float* id_emb  = (const float*)d_in[6];
  const float* id_g    = (const float*)d_in[7];
  const float* id_b    = (const float*)d_in[8];
  const float* text_W  = (const float*)d_in[9];
  const float* text_b  = (const float*)d_in[10];
  const float* text_g  = (const float*)d_in[11];
  const float* text_bb = (const float*)d_in[12];

  float* out = (float*)d_out;
  float* o_scores = out;                      // [256][50000]
  float* o_s1     = out + 12800000;
  float* o_s2     = out + 25600000;
  float* o_item   = out + 38400000;           // [50000][128]
  float* o_gnn    = out + 44800000;
  float* o_xmap   = out + 51200000;

  float* seT = (float*)d_ws;                  // [128][256]
  float* sfT = seT + 32768;
  __bf16* wp   = (__bf16*)((char*)d_ws + 262144);
  __bf16* wqkv = wp;                          // 4 mats x 49152
  __bf16* wo   = wp + 196608;                 // 4 x 16384
  __bf16* w1p  = wp + 262144;                 // 4 x 65536
  __bf16* w2p  = wp + 524288;                 // 4 x 65536
  __bf16* wtx  = wp + 786432;                 // 98304

  // weight prep (bf16, fragment-major); mat order = [enc][layer]
  prep_w<<<96, 256, 0, stream>>>((const float*)d_in[16], (const float*)d_in[31], wqkv, 128, 384, 4);
  prep_w<<<32, 256, 0, stream>>>((const float*)d_in[18], (const float*)d_in[33], wo,   128, 128, 4);
  prep_w<<<128,256, 0, stream>>>((const float*)d_in[22], (const float*)d_in[37], w1p,  128, 512, 4);
  prep_w<<<128,256, 0, stream>>>((const float*)d_in[24], (const float*)d_in[39], w2p,  512, 128, 4);
  prep_w<<<48, 256, 0, stream>>>(text_W, text_W, wtx, 768, 128, 1);

  ln_kernel<<<12500, 256, 0, stream>>>(id_emb, o_item, o_gnn, id_g, id_b, 50000);
  xmap_mfma<<<782, 256, 0, stream>>>(x, wtx, text_b, o_xmap);
  ln_kernel<<<12500, 256, 0, stream>>>(o_xmap, o_xmap, nullptr, text_g, text_bb, 50000);

  EncP P0, P1;
  P0.pos = (const float*)d_in[13]; P0.ln0g = (const float*)d_in[14]; P0.ln0b = (const float*)d_in[15];
  P0.bqkv = (const float*)d_in[17]; P0.bo = (const float*)d_in[19];
  P0.ln1g = (const float*)d_in[20]; P0.ln1b = (const float*)d_in[21];
  P0.b1 = (const float*)d_in[23]; P0.b2 = (const float*)d_in[25];
  P0.ln2g = (const float*)d_in[26]; P0.ln2b = (const float*)d_in[27];
  P0.wq = wqkv; P0.wo = wo; P0.w1 = w1p; P0.w2 = w2p;
  P0.emb = o_item; P0.outT = seT;

  P1.pos = (const float*)d_in[28]; P1.ln0g = (const float*)d_in[29]; P1.ln0b = (const float*)d_in[30];
  P1.bqkv = (const float*)d_in[32]; P1.bo = (const float*)d_in[34];
  P1.ln1g = (const float*)d_in[35]; P1.ln1b = (const float*)d_in[36];
  P1.b1 = (const float*)d_in[38]; P1.b2 = (const float*)d_in[40];
  P1.ln2g = (const float*)d_in[41]; P1.ln2b = (const float*)d_in[42];
  P1.wq = wqkv + 2*49152; P1.wo = wo + 2*16384; P1.w1 = w1p + 2*65536; P1.w2 = w2p + 2*65536;
  P1.emb = o_xmap; P1.outT = sfT;

  encoder_mfma<<<512, 256, 0, stream>>>(P0, P1, itemid, mask);

  scores_kernel<<<3125, 256, 0, stream>>>(seT, sfT, o_item, o_xmap,
                                          o_scores, o_s1, o_s2);
}